// Round 1
// baseline (77.297 us; speedup 1.0000x reference)
//
#include <hip/hip_runtime.h>
#include <math.h>

#define N_NODES 2000
#define IN_FEATS 32
#define HID 64
#define OUT_F 16
#define CAT 96      // HID + MSG
#define START0 1000

// Closed form (see analysis): within the 16-pop horizon, states[start] is
// written exactly once (pop 0, msg = ones). nbr/deg/Wnm/bnm are dead.
//   h_i    = relu(Wns[:, :64] @ (We @ x_i + be) + Wns[:, 64:96].sum(1) + bns)  (i >= 1000)
//   out[i] = log_softmax(Wd @ h_i + bd),  h_i = 0 for i < 1000
__global__ __launch_bounds__(64) void gwac_closed_form(
    const float* __restrict__ x,    // [2000, 32]
    const float* __restrict__ We,   // [64, 32]
    const float* __restrict__ be,   // [64]
    const float* __restrict__ Wns,  // [64, 96]
    const float* __restrict__ bns,  // [64]
    const float* __restrict__ Wd,   // [16, 64]
    const float* __restrict__ bd,   // [16]
    float* __restrict__ out)        // [2000, 16]
{
    const int l   = threadIdx.x;    // 0..63, one wave per block
    const int j   = l & 15;         // class index this lane contributes to
    const int seg = l >> 4;         // which 16-chunk of h this lane covers

    __shared__ float xbuf[IN_FEATS];
    __shared__ float encbuf[HID];
    __shared__ float hbuf[HID];

    // ---- per-lane weight rows in registers (loaded once per block; L2/L3-hot) ----
    float wWe[IN_FEATS];
#pragma unroll
    for (int k = 0; k < IN_FEATS; ++k) wWe[k] = We[l * IN_FEATS + k];

    float wWns[HID];
#pragma unroll
    for (int k = 0; k < HID; ++k) wWns[k] = Wns[l * CAT + k];

    float cns = bns[l];
#pragma unroll
    for (int k = HID; k < CAT; ++k) cns += Wns[l * CAT + k];  // msg == ones fold

    float wWd[16];
#pragma unroll
    for (int k = 0; k < 16; ++k) wWd[k] = Wd[j * HID + seg * 16 + k];

    const float be_l = be[l];
    const float bd_j = bd[j];

    // Block b handles rows b (zero-state) and b+1000 (full path).
    for (int half = 0; half < 2; ++half) {
        const int i = blockIdx.x + half * START0;
        float logit;
        if (half == 1) {
            // encoder: enc[l] = be[l] + We[l,:] . x_i
            if (l < IN_FEATS) xbuf[l] = x[i * IN_FEATS + l];
            __syncthreads();
            float e = be_l;
#pragma unroll
            for (int k = 0; k < IN_FEATS; ++k) e += wWe[k] * xbuf[k];
            encbuf[l] = e;
            __syncthreads();
            // node-state: h[l] = relu(Wns[l,:64] . enc + cns)
            float h = cns;
#pragma unroll
            for (int k = 0; k < HID; ++k) h += wWns[k] * encbuf[k];
            h = fmaxf(h, 0.0f);
            hbuf[l] = h;
            __syncthreads();
            // logits: 4-way partials per class, xor-shuffle reduce over segs
            float p = 0.0f;
#pragma unroll
            for (int k = 0; k < 16; ++k) p += wWd[k] * hbuf[seg * 16 + k];
            p += __shfl_xor(p, 16);
            p += __shfl_xor(p, 32);
            logit = p + bd_j;
            __syncthreads();   // protect LDS buffers before any reuse
        } else {
            logit = bd_j;      // nodestates row is exactly zero
        }

        // log_softmax over the 16 classes (butterfly within each 16-lane group)
        float m = logit;
        m = fmaxf(m, __shfl_xor(m, 1));
        m = fmaxf(m, __shfl_xor(m, 2));
        m = fmaxf(m, __shfl_xor(m, 4));
        m = fmaxf(m, __shfl_xor(m, 8));
        const float ev = expf(logit - m);
        float s = ev;
        s += __shfl_xor(s, 1);
        s += __shfl_xor(s, 2);
        s += __shfl_xor(s, 4);
        s += __shfl_xor(s, 8);
        const float r = logit - m - logf(s);
        if (l < OUT_F) out[i * OUT_F + l] = r;
    }
}

extern "C" void kernel_launch(void* const* d_in, const int* in_sizes, int n_in,
                              void* d_out, int out_size, void* d_ws, size_t ws_size,
                              hipStream_t stream) {
    const float* x   = (const float*)d_in[0];
    // d_in[1] = nbr (int32), d_in[2] = deg (int32): dead within the 16-pop horizon
    const float* We  = (const float*)d_in[3];
    const float* be  = (const float*)d_in[4];
    const float* Wns = (const float*)d_in[5];
    const float* bns = (const float*)d_in[6];
    // d_in[7] = Wnm, d_in[8] = bnm: only produce messages; never reach states[start]
    const float* Wd  = (const float*)d_in[9];
    const float* bd  = (const float*)d_in[10];
    float* out = (float*)d_out;

    gwac_closed_form<<<START0, 64, 0, stream>>>(x, We, be, Wns, bns, Wd, bd, out);
}

// Round 2
// 77.193 us; speedup vs baseline: 1.0013x; 1.0013x over previous
//
#include <hip/hip_runtime.h>
#include <math.h>

#define N_NODES 2000
#define IN_FEATS 32
#define HID 64
#define OUT_F 16
#define CAT 96      // HID + MSG
#define START0 1000

// Closed form (verified absmax 0.0 in R1): within the 16-pop horizon,
// states[start] is written exactly once (pop 0, msg = ones); nbr/deg/Wnm/bnm
// are dead w.r.t. the output.
//   h_i    = relu(Wns[:, :64] @ (We @ x_i + be) + Wns[:, 64:96].sum(1) + bns)  (i >= 1000)
//   out[i] = log_softmax(Wd @ h_i + bd),  h_i = 0 for i < 1000
//
// R2 structure: one WAVE per high row (no LDS, no __syncthreads — all
// broadcasts via __shfl/ds_bpermute), 4 waves per 256-thread block, grid 250.
// Per-lane weight rows loaded as float4 (global_load_dwordx4, L2-hot).
__global__ __launch_bounds__(256) void gwac_closed_form(
    const float* __restrict__ x,    // [2000, 32]
    const float* __restrict__ We,   // [64, 32]
    const float* __restrict__ be,   // [64]
    const float* __restrict__ Wns,  // [64, 96]
    const float* __restrict__ bns,  // [64]
    const float* __restrict__ Wd,   // [16, 64]
    const float* __restrict__ bd,   // [16]
    float* __restrict__ out)        // [2000, 16]
{
    const int l    = threadIdx.x & 63;                       // lane in wave
    const int wave = blockIdx.x * 4 + (threadIdx.x >> 6);    // 0..999
    const int j    = l & 15;         // class index this lane contributes to
    const int seg  = l >> 4;         // which 16-chunk of h this lane covers

    // ---- per-lane weight rows in registers, float4 loads (L2/L3-hot) ----
    float wWe[IN_FEATS];
    {
        const float4* p = (const float4*)(We + l * IN_FEATS);
#pragma unroll
        for (int q = 0; q < IN_FEATS / 4; ++q) {
            float4 v = p[q];
            wWe[q*4+0] = v.x; wWe[q*4+1] = v.y; wWe[q*4+2] = v.z; wWe[q*4+3] = v.w;
        }
    }
    float wWns[HID];
    float cns = bns[l];
    {
        const float4* p = (const float4*)(Wns + l * CAT);
#pragma unroll
        for (int q = 0; q < HID / 4; ++q) {
            float4 v = p[q];
            wWns[q*4+0] = v.x; wWns[q*4+1] = v.y; wWns[q*4+2] = v.z; wWns[q*4+3] = v.w;
        }
#pragma unroll
        for (int q = HID / 4; q < CAT / 4; ++q) {   // msg == ones fold
            float4 v = p[q];
            cns += v.x + v.y + v.z + v.w;
        }
    }
    float wWd[16];
    {
        const float4* p = (const float4*)(Wd + j * HID + seg * 16);
#pragma unroll
        for (int q = 0; q < 4; ++q) {
            float4 v = p[q];
            wWd[q*4+0] = v.x; wWd[q*4+1] = v.y; wWd[q*4+2] = v.z; wWd[q*4+3] = v.w;
        }
    }
    const float be_l = be[l];
    const float bd_j = bd[j];

    // ---- high row i = 1000 + wave: full closed-form path, shuffle-broadcast ----
    const int i = START0 + wave;
    float xv = (l < IN_FEATS) ? x[i * IN_FEATS + l] : 0.0f;  // coalesced

    float e = be_l;
#pragma unroll
    for (int k = 0; k < IN_FEATS; ++k) e = fmaf(wWe[k], __shfl(xv, k), e);

    float h = cns;
#pragma unroll
    for (int k = 0; k < HID; ++k) h = fmaf(wWns[k], __shfl(e, k), h);
    h = fmaxf(h, 0.0f);

    float p = 0.0f;
#pragma unroll
    for (int k = 0; k < 16; ++k) p = fmaf(wWd[k], __shfl(h, seg * 16 + k), p);
    p += __shfl_xor(p, 16);
    p += __shfl_xor(p, 32);
    const float logit_hi = p + bd_j;

    // ---- log_softmax butterfly over the 16-class groups, both rows ----
    // high row
    {
        float m = logit_hi;
        m = fmaxf(m, __shfl_xor(m, 1));
        m = fmaxf(m, __shfl_xor(m, 2));
        m = fmaxf(m, __shfl_xor(m, 4));
        m = fmaxf(m, __shfl_xor(m, 8));
        float s = expf(logit_hi - m);
        s += __shfl_xor(s, 1);
        s += __shfl_xor(s, 2);
        s += __shfl_xor(s, 4);
        s += __shfl_xor(s, 8);
        const float r = logit_hi - m - logf(s);
        if (l < OUT_F) out[i * OUT_F + l] = r;
    }
    // low row (wave < 1000): h == 0 -> logits == bd, identical for all rows
    {
        const float logit_lo = bd_j;
        float m = logit_lo;
        m = fmaxf(m, __shfl_xor(m, 1));
        m = fmaxf(m, __shfl_xor(m, 2));
        m = fmaxf(m, __shfl_xor(m, 4));
        m = fmaxf(m, __shfl_xor(m, 8));
        float s = expf(logit_lo - m);
        s += __shfl_xor(s, 1);
        s += __shfl_xor(s, 2);
        s += __shfl_xor(s, 4);
        s += __shfl_xor(s, 8);
        const float r = logit_lo - m - logf(s);
        if (l < OUT_F) out[wave * OUT_F + l] = r;
    }
}

extern "C" void kernel_launch(void* const* d_in, const int* in_sizes, int n_in,
                              void* d_out, int out_size, void* d_ws, size_t ws_size,
                              hipStream_t stream) {
    const float* x   = (const float*)d_in[0];
    // d_in[1] = nbr, d_in[2] = deg: dead within the 16-pop horizon
    const float* We  = (const float*)d_in[3];
    const float* be  = (const float*)d_in[4];
    const float* Wns = (const float*)d_in[5];
    const float* bns = (const float*)d_in[6];
    // d_in[7] = Wnm, d_in[8] = bnm: messages never reach states[start]
    const float* Wd  = (const float*)d_in[9];
    const float* bd  = (const float*)d_in[10];
    float* out = (float*)d_out;

    gwac_closed_form<<<250, 256, 0, stream>>>(x, We, be, Wns, bns, Wd, bd, out);
}